// Round 5
// baseline (205.719 us; speedup 1.0000x reference)
//
#include <hip/hip_runtime.h>
#include <hip/hip_bf16.h>
#include <math.h>

#define B_ 64
#define N_ 64
#define C_ 8
#define F_ 256
#define K_ 2048    // C_*F_
#define NO_ 2048   // OC_*OF_
#define M_TOT 4160 // 64 (zx rows) + 4096 (zn rows)

typedef __attribute__((ext_vector_type(8))) short bf16x8;  // 8 bf16 = 4 VGPRs
typedef __attribute__((ext_vector_type(4))) float f32x4;

__device__ __forceinline__ unsigned short bfbits(float f) {
    union { __hip_bfloat16 h; unsigned short u; } cv;
    cv.h = __float2bfloat16(f);
    return cv.u;
}

// ---------------------------------------------------------------------------
// Fused: s1[b], s2[b,n] reductions + Wc fp32->bf16 conversion.
// blk < 4096: s2;  4096..4159: s1;  >=4160: wc convert.
__global__ __launch_bounds__(256) void sums_wc_k(const float* __restrict__ x,
        const float* __restrict__ nb, const float* __restrict__ W1,
        const float* __restrict__ W2, const float* __restrict__ Wc,
        float* __restrict__ s1, float* __restrict__ s2,
        __hip_bfloat16* __restrict__ Bbuf) {
    int blk = blockIdx.x;
    int f = threadIdx.x;
    if (blk >= B_ * N_ + B_) {
        int i = (blk - (B_ * N_ + B_)) * 1024 + f * 4;
        float4 v = *(const float4*)(Wc + i);
        ushort4 u = { bfbits(v.x), bfbits(v.y), bfbits(v.z), bfbits(v.w) };
        *(ushort4*)(&Bbuf[i]) = u;            // one 8B store (was 4x 2B)
        return;
    }
    float val;
    if (blk < B_ * N_) {
        const float* base = nb + (size_t)blk * (C_ * F_);
        float wsum = 0.f;
        #pragma unroll
        for (int k = 0; k < C_; ++k) wsum += W2[k * F_ + f];
        float cs = 0.f;
        #pragma unroll
        for (int c = 0; c < C_; ++c) cs += base[c * F_ + f];
        val = cs * wsum;
    } else {
        int b = blk - B_ * N_;
        const float* base = x + (size_t)b * (C_ * F_);
        float wsum = 0.f;
        #pragma unroll
        for (int k = 0; k < C_; ++k) wsum += W1[k * F_ + f];
        float cs = 0.f;
        #pragma unroll
        for (int c = 0; c < C_; ++c) cs += base[c * F_ + f];
        val = cs * wsum;
    }
    #pragma unroll
    for (int off = 32; off > 0; off >>= 1) val += __shfl_down(val, off, 64);
    __shared__ float wred[4];
    int w = f >> 6;
    if ((f & 63) == 0) wred[w] = val;
    __syncthreads();
    if (f == 0) {
        float s = wred[0] + wred[1] + wred[2] + wred[3];
        if (blk < B_ * N_) s2[blk] = s;
        else s1[blk - B_ * N_] = s;
    }
}

// ---------------------------------------------------------------------------
// t[b,c,d] = s1[b] * sum_n nb[b,n,c,d] * s2[b,n]
__global__ __launch_bounds__(1024) void t_k(const float* __restrict__ nb,
        const float* __restrict__ s1, const float* __restrict__ s2,
        float* __restrict__ t) {
    int blk = blockIdx.x;  // b*C_ + c
    int b = blk / C_, c = blk % C_;
    int tid = threadIdx.x;
    int q = tid >> 8, d = tid & 255;
    const float* p = nb + ((size_t)(b * N_) * C_ + c) * F_ + d;
    const float* s2p = s2 + b * N_;
    float acc = 0.f;
    #pragma unroll
    for (int j = 0; j < 16; ++j) {
        int n = q * 16 + j;
        acc += p[(size_t)n * C_ * F_] * s2p[n];
    }
    __shared__ float part[4][F_];
    part[q][d] = acc;
    __syncthreads();
    if (tid < 256) {
        float s = part[0][d] + part[1][d] + part[2][d] + part[3][d];
        t[(size_t)blk * F_ + d] = s * s1[b];
    }
}

// ---------------------------------------------------------------------------
// rdenom[b,a,d] = 1 / (1e-7 + sum_c |sgnroot(x_a t_d + x_d t_a)|)
__global__ __launch_bounds__(256) void denom_k(const float* __restrict__ x,
        const float* __restrict__ t, float* __restrict__ rdenom) {
    int blk = blockIdx.x;  // b*F_ + a
    int b = blk >> 8, a = blk & 255;
    int d = threadIdx.x;
    float acc = 1e-7f;
    #pragma unroll
    for (int c = 0; c < C_; ++c) {
        size_t o = ((size_t)b * C_ + c) * F_;
        float xa = x[o + a], ta = t[o + a];
        float xd = x[o + d], td = t[o + d];
        float v = xa * td + xd * ta;
        float r = __builtin_amdgcn_sqrtf(fmaxf(fabsf(v), 1e-8f));
        acc += (v != 0.f) ? r : 0.f;
    }
    rdenom[(size_t)blk * F_ + d] = __builtin_amdgcn_rcpf(acc);
}

__device__ __forceinline__ float sgnroot_dev(float v) {
    float r = __builtin_amdgcn_sqrtf(fmaxf(fabsf(v), 1e-8f));
    return (v > 0.f) ? r : ((v < 0.f) ? -r : 0.f);
}

// ---------------------------------------------------------------------------
// Fused zx+zn via MFMA. One block per (b,c).
// R3 (verified, kept): packed 8B LDS staging writes; all-atile register
// accumulators; LDS-staged epilogue with coalesced 512B row copy-out.
#define ZNX_PAD 264  // row STRIDE in bf16: 256 data + 8 pad
__global__ __launch_bounds__(256, 2) void znx_k(const float* __restrict__ x,
        const float* __restrict__ t, const float* __restrict__ rdenom,
        const float* __restrict__ nb, __hip_bfloat16* __restrict__ Abuf) {
    int bc = blockIdx.x;
    int b = bc >> 3, c = bc & 7;
    int tid = threadIdx.x;
    int wave = tid >> 6, lane = tid & 63;
    __shared__ float xs[F_], ts[F_];
    __shared__ __hip_bfloat16 nbB[80 * ZNX_PAD];  // 42240 B

    xs[tid] = x[(size_t)bc * F_ + tid];
    ts[tid] = t[(size_t)bc * F_ + tid];
    {
        int r = tid >> 2, cs0 = (tid & 3) * 64;
        const float* src = nb + (((size_t)(b * N_ + r)) * C_ + c) * F_ + cs0;
        __hip_bfloat16* dst = nbB + r * ZNX_PAD + cs0;
        #pragma unroll
        for (int j = 0; j < 64; j += 4) {
            float4 v = *(const float4*)(src + j);
            ushort4 u = { bfbits(v.x), bfbits(v.y), bfbits(v.z), bfbits(v.w) };
            *(ushort4*)(&dst[j]) = u;          // 8B-aligned packed write
        }
    }
    if (tid < 64) {
        float4 v = *(const float4*)(x + (size_t)bc * F_ + tid * 4);
        ushort4 u = { bfbits(v.x), bfbits(v.y), bfbits(v.z), bfbits(v.w) };
        *(ushort4*)(&nbB[64 * ZNX_PAD + tid * 4]) = u;
    }
    {
        __hip_bfloat16 z = __float2bfloat16(0.f);
        #pragma unroll
        for (int j = 0; j < 16; ++j) {
            int o = 65 * ZNX_PAD + tid * 16 + j;
            if (o < 80 * ZNX_PAD) nbB[o] = z;
        }
    }
    __syncthreads();

    const int aq = lane & 15;
    const int dq = lane >> 4;
    f32x4 acc[4][5] = {};   // [atile][mt] -- all compile-time indexed
    #pragma unroll
    for (int atile = 0; atile < 4; ++atile) {
        int a = wave * 64 + atile * 16 + aq;
        float xa = xs[a], ta = ts[a];
        const float* drow = rdenom + ((size_t)b * F_ + a) * F_;
        #pragma unroll
        for (int kc = 0; kc < 8; ++kc) {
            int d0 = kc * 32 + dq * 8;
            float4 xv0 = *(const float4*)(xs + d0);
            float4 xv1 = *(const float4*)(xs + d0 + 4);
            float4 tv0 = *(const float4*)(ts + d0);
            float4 tv1 = *(const float4*)(ts + d0 + 4);
            float4 dn0 = *(const float4*)(drow + d0);
            float4 dn1 = *(const float4*)(drow + d0 + 4);
            float xv[8] = {xv0.x, xv0.y, xv0.z, xv0.w, xv1.x, xv1.y, xv1.z, xv1.w};
            float tv[8] = {tv0.x, tv0.y, tv0.z, tv0.w, tv1.x, tv1.y, tv1.z, tv1.w};
            float dn[8] = {dn0.x, dn0.y, dn0.z, dn0.w, dn1.x, dn1.y, dn1.z, dn1.w};
            union { bf16x8 v; __hip_bfloat16 h[8]; } bu;
            #pragma unroll
            for (int j = 0; j < 8; ++j) {
                float g = sgnroot_dev(xa * tv[j] + xv[j] * ta);
                bu.h[j] = __float2bfloat16(g * dn[j]);   // dn = 1/denom
            }
            #pragma unroll
            for (int mt = 0; mt < 5; ++mt) {
                bf16x8 af = *(const bf16x8*)(nbB + (mt * 16 + aq) * ZNX_PAD
                                             + kc * 32 + dq * 8);
                acc[atile][mt] = __builtin_amdgcn_mfma_f32_16x16x32_bf16(
                    af, bu.v, acc[atile][mt], 0, 0, 0);
            }
        }
    }

    // ---- epilogue: stage [65 rows x 256 cols] bf16 tile into nbB, then
    //      copy out as full coalesced rows (one 512B row per wave per iter).
    __syncthreads();   // all waves done READING nbB before overwrite
    #pragma unroll
    for (int atile = 0; atile < 4; ++atile) {
        int a = wave * 64 + atile * 16 + aq;
        #pragma unroll
        for (int mt = 0; mt < 4; ++mt) {
            #pragma unroll
            for (int i = 0; i < 4; ++i) {
                int n = mt * 16 + dq * 4 + i;
                nbB[n * ZNX_PAD + a] = __float2bfloat16(acc[atile][mt][i]);
            }
        }
        if (dq == 0)
            nbB[64 * ZNX_PAD + a] = __float2bfloat16(acc[atile][4][0]);
    }
    __syncthreads();
    // 65 rows x 512B = 4160 8B-chunks; chunk q -> row q>>6, bf16 off (q&63)*4
    for (int it = 0; it < 17; ++it) {
        int q = it * 256 + tid;
        if (q < 4160) {
            int row = q >> 6;
            int off = (q & 63) * 4;
            ushort4 u = *(const ushort4*)(&nbB[row * ZNX_PAD + off]);
            int grow = (row < 64) ? (64 + b * N_ + row) : b;
            *(ushort4*)(&Abuf[(size_t)grow * K_ + c * F_ + off]) = u;
        }
    }
}

// ---------------------------------------------------------------------------
// C[M_TOT, 2048] = A[M_TOT, 2048] @ B[2048, 2048]^T, bf16 in, fp32 out.
// SWIZZLED row-major LDS (staging coalesced + reads conflict-free,
// SQ_LDS_BANK_CONFLICT == 0 verified). Counted-vmcnt pipeline (T3+T4,
// verified R2/R4). R5: REGISTER double-buffered fragments -- each slot
// issues ds_reads for tile t+1, then runs tile t's MFMAs reg-only, so
// LDS-read latency hides under the matrix pipe (m133 technique; its
// prerequisite regime -- no vmcnt(0) drain -- now holds). LDS back to
// 3 buffers (48 KiB) + launch_bounds(256,3): 3 blocks/CU -> all 528
// blocks co-resident, removing the 16-CU 3-block sequential tail.
__global__ __launch_bounds__(256, 3) void gemm_bf16_k(
        const __hip_bfloat16* __restrict__ A,
        const __hip_bfloat16* __restrict__ Bm,
        float* __restrict__ Cm) {
    __shared__ char lds[49152] __attribute__((aligned(16)));  // 3 x (8K A + 8K B)
    const int t = threadIdx.x;
    const int wave = t >> 6;
    const int lane = t & 63;
    const int col0 = blockIdx.x * 128;
    const int row0 = blockIdx.y * 128;
    const int wrow0 = (wave & 1) * 64;
    const int wcol0 = (wave >> 1) * 64;
    const int aq = lane & 15;
    const int dq = lane >> 4;

    const int rA0 = t >> 2;                               // row 0..63 (issue 0)
    const int kcs = ((t & 3) - ((t >> 3) & 3)) & 3;       // swizzled k-chunk
    const int kc = kcs * 8;                               // element offset
    const int grA0 = min(row0 + rA0, M_TOT - 1);
    const int grA1 = min(row0 + rA0 + 64, M_TOT - 1);
    const int gcB0 = col0 + rA0;
    const int gcB1 = col0 + rA0 + 64;
    const size_t aoff0 = (size_t)grA0 * K_ + kc;
    const size_t aoff1 = (size_t)grA1 * K_ + kc;
    const size_t boff0 = (size_t)gcB0 * K_ + kc;
    const size_t boff1 = (size_t)gcB1 * K_ + kc;
    const int swz = ((dq + (aq >> 1)) & 3) * 16;          // read-side position
    const int ldsw = wave * 1024;

    f32x4 acc[4][4] = {};
    bf16x8 afr[2][4], bfr[2][4];   // register-double-buffered fragments

#define STAGE(BI, TK) do {                                                     \
    const int k0_ = (TK) * 32;                                                 \
    char* la_ = lds + (BI) * 16384 + ldsw;                                     \
    char* lb_ = la_ + 8192;                                                    \
    __builtin_amdgcn_global_load_lds(                                          \
        (const __attribute__((address_space(1))) void*)(A + aoff0 + k0_),      \
        (__attribute__((address_space(3))) void*)la_, 16, 0, 0);               \
    __builtin_amdgcn_global_load_lds(                                          \
        (const __attribute__((address_space(1))) void*)(A + aoff1 + k0_),      \
        (__attribute__((address_space(3))) void*)(la_ + 4096), 16, 0, 0);      \
    __builtin_amdgcn_global_load_lds(                                          \
        (const __attribute__((address_space(1))) void*)(Bm + boff0 + k0_),     \
        (__attribute__((address_space(3))) void*)lb_, 16, 0, 0);               \
    __builtin_amdgcn_global_load_lds(                                          \
        (const __attribute__((address_space(1))) void*)(Bm + boff1 + k0_),     \
        (__attribute__((address_space(3))) void*)(lb_ + 4096), 16, 0, 0);      \
} while (0)

// Issue LDS->reg fragment loads for buffer BI into reg-set RI (no wait).
#define DSREAD(BI, RI) do {                                                    \
    const char* la_ = lds + (BI) * 16384;                                      \
    const char* lb_ = la_ + 8192;                                              \
    _Pragma("unroll")                                                          \
    for (int rb = 0; rb < 4; ++rb)                                             \
        afr[RI][rb] = *(const bf16x8*)(la_ + (wrow0 + rb * 16 + aq) * 64 + swz);\
    _Pragma("unroll")                                                          \
    for (int cb = 0; cb < 4; ++cb)                                             \
        bfr[RI][cb] = *(const bf16x8*)(lb_ + (wcol0 + cb * 16 + aq) * 64 + swz);\
} while (0)

// 16 reg-only MFMAs on reg-set RI (compiler inserts the precise lgkmcnt).
#define MFMAS(RI) do {                                                         \
    _Pragma("unroll")                                                          \
    for (int rb = 0; rb < 4; ++rb)                                             \
        _Pragma("unroll")                                                      \
        for (int cb = 0; cb < 4; ++cb)                                         \
            acc[rb][cb] = __builtin_amdgcn_mfma_f32_16x16x32_bf16(             \
                afr[RI][rb], bfr[RI][cb], acc[rb][cb], 0, 0, 0);               \
} while (0)

#define WAITV(N) do {                                                          \
    asm volatile("s_waitcnt vmcnt(" #N ")" ::: "memory");                      \
    __builtin_amdgcn_sched_barrier(0);                                         \
    __builtin_amdgcn_s_barrier();                                              \
    __builtin_amdgcn_sched_barrier(0);                                         \
} while (0)

// All waves drain their own oldest 8 ds_reads (reads of the buffer about to
// be overwritten), then barrier -> safe to STAGE over it.
#define LGKM8BAR do {                                                          \
    asm volatile("s_waitcnt lgkmcnt(8)" ::: "memory");                         \
    __builtin_amdgcn_sched_barrier(0);                                         \
    __builtin_amdgcn_s_barrier();                                              \
    __builtin_amdgcn_sched_barrier(0);                                         \
} while (0)

// Slot: wait tile t+1 staged -> prefetch its frags -> protect buf[t%3] ->
// refill it with tile t+3 -> compute tile t (reg-only MFMA).
#define SLOT(BN, RN, BS, RC, TKS) do {                                         \
    WAITV(4);                                                                  \
    DSREAD(BN, RN);                                                            \
    LGKM8BAR;                                                                  \
    STAGE(BS, TKS);                                                            \
    MFMAS(RC);                                                                 \
} while (0)

    // Prologue: fill 3-deep LDS pipeline, load tile 0 fragments.
    STAGE(0, 0);
    STAGE(1, 1);
    STAGE(2, 2);
    asm volatile("s_waitcnt vmcnt(8)" ::: "memory");
    __builtin_amdgcn_sched_barrier(0);
    __builtin_amdgcn_s_barrier();
    __builtin_amdgcn_sched_barrier(0);
    DSREAD(0, 0);

    // Main: slots 0..59, period-6 unroll (buf = slot%3, reg = slot&1 static).
    for (int s6 = 0; s6 < 60; s6 += 6) {
        SLOT(1, 1, 0, 0, s6 + 3);
        SLOT(2, 0, 1, 1, s6 + 4);
        SLOT(0, 1, 2, 0, s6 + 5);
        SLOT(1, 0, 0, 1, s6 + 6);
        SLOT(2, 1, 1, 0, s6 + 7);
        SLOT(0, 0, 2, 1, s6 + 8);
    }
    // Epilogue: slots 60..63.
    SLOT(1, 1, 0, 0, 63);          // slot 60: stages tile 63 into buf0
    WAITV(4);                      // slot 61: tile 62 landed
    DSREAD(2, 0);
    MFMAS(1);
    WAITV(0);                      // slot 62: tile 63 landed
    DSREAD(0, 1);
    MFMAS(0);
    MFMAS(1);                      // slot 63

#undef STAGE
#undef DSREAD
#undef MFMAS
#undef WAITV
#undef LGKM8BAR
#undef SLOT

    #pragma unroll
    for (int rb = 0; rb < 4; ++rb) {
        int rowbase = row0 + wrow0 + rb * 16 + (lane >> 4) * 4;
        #pragma unroll
        for (int cb = 0; cb < 4; ++cb) {
            int col = col0 + wcol0 + cb * 16 + (lane & 15);
            #pragma unroll
            for (int i = 0; i < 4; ++i) {
                int row = rowbase + i;
                if (row < M_TOT)
                    Cm[(size_t)row * NO_ + col] = acc[rb][cb][i];
            }
        }
    }
}

// ---------------------------------------------------------------------------
extern "C" void kernel_launch(void* const* d_in, const int* in_sizes, int n_in,
                              void* d_out, int out_size, void* d_ws, size_t ws_size,
                              hipStream_t stream) {
    const float* x  = (const float*)d_in[0];
    const float* nb = (const float*)d_in[1];
    const float* W1 = (const float*)d_in[2];
    const float* W2 = (const float*)d_in[3];
    const float* Wc = (const float*)d_in[4];
    float* out = (float*)d_out;
    float* ws = (float*)d_ws;

    float* s1    = ws;            // 64 f
    float* s2    = ws + 64;       // 4096 f
    float* t     = ws + 4160;     // 131072 f
    float* rden  = ws + 135232;   // 4194304 f (B*F*F), stores 1/denom
    __hip_bfloat16* Abuf = (__hip_bfloat16*)(ws + 4329536);   // 4160*2048 bf16
    __hip_bfloat16* Bbuf = Abuf + (size_t)M_TOT * K_;         // 2048*2048 bf16

    hipLaunchKernelGGL(sums_wc_k, dim3(B_ * N_ + B_ + (K_ * NO_) / 1024),
                       dim3(256), 0, stream, x, nb, W1, W2, Wc, s1, s2, Bbuf);
    hipLaunchKernelGGL(t_k, dim3(B_ * C_), dim3(1024), 0, stream, nb, s1, s2, t);
    hipLaunchKernelGGL(denom_k, dim3(B_ * F_), dim3(256), 0, stream, x, t, rden);
    hipLaunchKernelGGL(znx_k, dim3(B_ * C_), dim3(256), 0, stream,
                       x, t, rden, nb, Abuf);
    hipLaunchKernelGGL(gemm_bf16_k, dim3(16, 33), dim3(256), 0, stream,
                       Abuf, Bbuf, out);
}

// Round 6
// 199.657 us; speedup vs baseline: 1.0304x; 1.0304x over previous
//
#include <hip/hip_runtime.h>
#include <hip/hip_bf16.h>
#include <math.h>

#define B_ 64
#define N_ 64
#define C_ 8
#define F_ 256
#define K_ 2048    // C_*F_
#define NO_ 2048   // OC_*OF_
#define M_TOT 4160 // 64 (zx rows) + 4096 (zn rows)

typedef __attribute__((ext_vector_type(8))) short bf16x8;  // 8 bf16 = 4 VGPRs
typedef __attribute__((ext_vector_type(4))) float f32x4;

__device__ __forceinline__ unsigned short bfbits(float f) {
    union { __hip_bfloat16 h; unsigned short u; } cv;
    cv.h = __float2bfloat16(f);
    return cv.u;
}

// ---------------------------------------------------------------------------
// Fused: s1[b], s2[b,n] reductions + Wc fp32->bf16 conversion.
// blk < 4096: s2;  4096..4159: s1;  >=4160: wc convert.
__global__ __launch_bounds__(256) void sums_wc_k(const float* __restrict__ x,
        const float* __restrict__ nb, const float* __restrict__ W1,
        const float* __restrict__ W2, const float* __restrict__ Wc,
        float* __restrict__ s1, float* __restrict__ s2,
        __hip_bfloat16* __restrict__ Bbuf) {
    int blk = blockIdx.x;
    int f = threadIdx.x;
    if (blk >= B_ * N_ + B_) {
        int i = (blk - (B_ * N_ + B_)) * 1024 + f * 4;
        float4 v = *(const float4*)(Wc + i);
        ushort4 u = { bfbits(v.x), bfbits(v.y), bfbits(v.z), bfbits(v.w) };
        *(ushort4*)(&Bbuf[i]) = u;            // one 8B store (was 4x 2B)
        return;
    }
    float val;
    if (blk < B_ * N_) {
        const float* base = nb + (size_t)blk * (C_ * F_);
        float wsum = 0.f;
        #pragma unroll
        for (int k = 0; k < C_; ++k) wsum += W2[k * F_ + f];
        float cs = 0.f;
        #pragma unroll
        for (int c = 0; c < C_; ++c) cs += base[c * F_ + f];
        val = cs * wsum;
    } else {
        int b = blk - B_ * N_;
        const float* base = x + (size_t)b * (C_ * F_);
        float wsum = 0.f;
        #pragma unroll
        for (int k = 0; k < C_; ++k) wsum += W1[k * F_ + f];
        float cs = 0.f;
        #pragma unroll
        for (int c = 0; c < C_; ++c) cs += base[c * F_ + f];
        val = cs * wsum;
    }
    #pragma unroll
    for (int off = 32; off > 0; off >>= 1) val += __shfl_down(val, off, 64);
    __shared__ float wred[4];
    int w = f >> 6;
    if ((f & 63) == 0) wred[w] = val;
    __syncthreads();
    if (f == 0) {
        float s = wred[0] + wred[1] + wred[2] + wred[3];
        if (blk < B_ * N_) s2[blk] = s;
        else s1[blk - B_ * N_] = s;
    }
}

// ---------------------------------------------------------------------------
// t[b,c,d] = s1[b] * sum_n nb[b,n,c,d] * s2[b,n]
__global__ __launch_bounds__(1024) void t_k(const float* __restrict__ nb,
        const float* __restrict__ s1, const float* __restrict__ s2,
        float* __restrict__ t) {
    int blk = blockIdx.x;  // b*C_ + c
    int b = blk / C_, c = blk % C_;
    int tid = threadIdx.x;
    int q = tid >> 8, d = tid & 255;
    const float* p = nb + ((size_t)(b * N_) * C_ + c) * F_ + d;
    const float* s2p = s2 + b * N_;
    float acc = 0.f;
    #pragma unroll
    for (int j = 0; j < 16; ++j) {
        int n = q * 16 + j;
        acc += p[(size_t)n * C_ * F_] * s2p[n];
    }
    __shared__ float part[4][F_];
    part[q][d] = acc;
    __syncthreads();
    if (tid < 256) {
        float s = part[0][d] + part[1][d] + part[2][d] + part[3][d];
        t[(size_t)blk * F_ + d] = s * s1[b];
    }
}

// ---------------------------------------------------------------------------
// rdenom[b,a,d] = 1 / (1e-7 + sum_c |sgnroot(x_a t_d + x_d t_a)|)
__global__ __launch_bounds__(256) void denom_k(const float* __restrict__ x,
        const float* __restrict__ t, float* __restrict__ rdenom) {
    int blk = blockIdx.x;  // b*F_ + a
    int b = blk >> 8, a = blk & 255;
    int d = threadIdx.x;
    float acc = 1e-7f;
    #pragma unroll
    for (int c = 0; c < C_; ++c) {
        size_t o = ((size_t)b * C_ + c) * F_;
        float xa = x[o + a], ta = t[o + a];
        float xd = x[o + d], td = t[o + d];
        float v = xa * td + xd * ta;
        float r = __builtin_amdgcn_sqrtf(fmaxf(fabsf(v), 1e-8f));
        acc += (v != 0.f) ? r : 0.f;
    }
    rdenom[(size_t)blk * F_ + d] = __builtin_amdgcn_rcpf(acc);
}

__device__ __forceinline__ float sgnroot_dev(float v) {
    float r = __builtin_amdgcn_sqrtf(fmaxf(fabsf(v), 1e-8f));
    return (v > 0.f) ? r : ((v < 0.f) ? -r : 0.f);
}

// ---------------------------------------------------------------------------
// Fused zx+zn via MFMA. One block per (b,c).
// R3 (verified, kept): packed 8B LDS staging writes; all-atile register
// accumulators; LDS-staged epilogue with coalesced 512B row copy-out.
#define ZNX_PAD 264  // row STRIDE in bf16: 256 data + 8 pad
__global__ __launch_bounds__(256, 2) void znx_k(const float* __restrict__ x,
        const float* __restrict__ t, const float* __restrict__ rdenom,
        const float* __restrict__ nb, __hip_bfloat16* __restrict__ Abuf) {
    int bc = blockIdx.x;
    int b = bc >> 3, c = bc & 7;
    int tid = threadIdx.x;
    int wave = tid >> 6, lane = tid & 63;
    __shared__ float xs[F_], ts[F_];
    __shared__ __hip_bfloat16 nbB[80 * ZNX_PAD];  // 42240 B

    xs[tid] = x[(size_t)bc * F_ + tid];
    ts[tid] = t[(size_t)bc * F_ + tid];
    {
        int r = tid >> 2, cs0 = (tid & 3) * 64;
        const float* src = nb + (((size_t)(b * N_ + r)) * C_ + c) * F_ + cs0;
        __hip_bfloat16* dst = nbB + r * ZNX_PAD + cs0;
        #pragma unroll
        for (int j = 0; j < 64; j += 4) {
            float4 v = *(const float4*)(src + j);
            ushort4 u = { bfbits(v.x), bfbits(v.y), bfbits(v.z), bfbits(v.w) };
            *(ushort4*)(&dst[j]) = u;          // 8B-aligned packed write
        }
    }
    if (tid < 64) {
        float4 v = *(const float4*)(x + (size_t)bc * F_ + tid * 4);
        ushort4 u = { bfbits(v.x), bfbits(v.y), bfbits(v.z), bfbits(v.w) };
        *(ushort4*)(&nbB[64 * ZNX_PAD + tid * 4]) = u;
    }
    {
        __hip_bfloat16 z = __float2bfloat16(0.f);
        #pragma unroll
        for (int j = 0; j < 16; ++j) {
            int o = 65 * ZNX_PAD + tid * 16 + j;
            if (o < 80 * ZNX_PAD) nbB[o] = z;
        }
    }
    __syncthreads();

    const int aq = lane & 15;
    const int dq = lane >> 4;
    f32x4 acc[4][5] = {};   // [atile][mt] -- all compile-time indexed
    #pragma unroll
    for (int atile = 0; atile < 4; ++atile) {
        int a = wave * 64 + atile * 16 + aq;
        float xa = xs[a], ta = ts[a];
        const float* drow = rdenom + ((size_t)b * F_ + a) * F_;
        #pragma unroll
        for (int kc = 0; kc < 8; ++kc) {
            int d0 = kc * 32 + dq * 8;
            float4 xv0 = *(const float4*)(xs + d0);
            float4 xv1 = *(const float4*)(xs + d0 + 4);
            float4 tv0 = *(const float4*)(ts + d0);
            float4 tv1 = *(const float4*)(ts + d0 + 4);
            float4 dn0 = *(const float4*)(drow + d0);
            float4 dn1 = *(const float4*)(drow + d0 + 4);
            float xv[8] = {xv0.x, xv0.y, xv0.z, xv0.w, xv1.x, xv1.y, xv1.z, xv1.w};
            float tv[8] = {tv0.x, tv0.y, tv0.z, tv0.w, tv1.x, tv1.y, tv1.z, tv1.w};
            float dn[8] = {dn0.x, dn0.y, dn0.z, dn0.w, dn1.x, dn1.y, dn1.z, dn1.w};
            union { bf16x8 v; __hip_bfloat16 h[8]; } bu;
            #pragma unroll
            for (int j = 0; j < 8; ++j) {
                float g = sgnroot_dev(xa * tv[j] + xv[j] * ta);
                bu.h[j] = __float2bfloat16(g * dn[j]);   // dn = 1/denom
            }
            #pragma unroll
            for (int mt = 0; mt < 5; ++mt) {
                bf16x8 af = *(const bf16x8*)(nbB + (mt * 16 + aq) * ZNX_PAD
                                             + kc * 32 + dq * 8);
                acc[atile][mt] = __builtin_amdgcn_mfma_f32_16x16x32_bf16(
                    af, bu.v, acc[atile][mt], 0, 0, 0);
            }
        }
    }

    // ---- epilogue: stage [65 rows x 256 cols] bf16 tile into nbB, then
    //      copy out as full coalesced rows (one 512B row per wave per iter).
    __syncthreads();   // all waves done READING nbB before overwrite
    #pragma unroll
    for (int atile = 0; atile < 4; ++atile) {
        int a = wave * 64 + atile * 16 + aq;
        #pragma unroll
        for (int mt = 0; mt < 4; ++mt) {
            #pragma unroll
            for (int i = 0; i < 4; ++i) {
                int n = mt * 16 + dq * 4 + i;
                nbB[n * ZNX_PAD + a] = __float2bfloat16(acc[atile][mt][i]);
            }
        }
        if (dq == 0)
            nbB[64 * ZNX_PAD + a] = __float2bfloat16(acc[atile][4][0]);
    }
    __syncthreads();
    // 65 rows x 512B = 4160 8B-chunks; chunk q -> row q>>6, bf16 off (q&63)*4
    for (int it = 0; it < 17; ++it) {
        int q = it * 256 + tid;
        if (q < 4160) {
            int row = q >> 6;
            int off = (q & 63) * 4;
            ushort4 u = *(const ushort4*)(&nbB[row * ZNX_PAD + off]);
            int grow = (row < 64) ? (64 + b * N_ + row) : b;
            *(ushort4*)(&Abuf[(size_t)grow * K_ + c * F_ + off]) = u;
        }
    }
}

// ---------------------------------------------------------------------------
// C[M_TOT, 2048] = A[M_TOT, 2048] @ B[2048, 2048]^T, bf16 in, fp32 out.
// SWIZZLED row-major LDS (staging coalesced + reads conflict-free,
// SQ_LDS_BANK_CONFLICT == 0 verified). Counted-vmcnt 3-deep pipeline with
// register-double-buffered fragments (R5 structure).
// R6: (a) SINGLE barrier per slot. The old second barrier only protected
//     the stage-target buffer from in-flight cross-wave ds_reads; since
//     every wave's reads of buf(t%3) were issued LAST slot (DSREAD(t)),
//     draining lgkmcnt(0) BEFORE the slot-entry barrier proves them all
//     complete -> STAGE after that one barrier is race-free.
//     Hazards re-audited: STAGE(t+3)->buf(t%3) vs DSREAD(t) [drained at
//     entry sync ✓]; DSREAD(t+1)->buf((t+1)%3) distinct from stage target
//     ✓; stage completion for DSREAD(t+3) guarded by vmcnt(4) at slot
//     t+2's entry ✓.
// (b) T1 XCD-aware block swizzle (528 % 8 == 0 -> simple bijective form):
//     consecutive intra-XCD blocks share the A row-panel, cutting the
//     3x HBM over-fetch (FETCH 77MB vs 25.5MB unique).
__global__ __launch_bounds__(256, 3) void gemm_bf16_k(
        const __hip_bfloat16* __restrict__ A,
        const __hip_bfloat16* __restrict__ Bm,
        float* __restrict__ Cm) {
    __shared__ char lds[49152] __attribute__((aligned(16)));  // 3 x (8K A + 8K B)
    const int t = threadIdx.x;
    const int wave = t >> 6;
    const int lane = t & 63;
    // T1: bijective XCD swizzle over 528 = 8 * 66 blocks.
    const int bidlin = blockIdx.y * 16 + blockIdx.x;
    const int bsw = (bidlin & 7) * 66 + (bidlin >> 3);
    const int col0 = (bsw & 15) * 128;
    const int row0 = (bsw >> 4) * 128;
    const int wrow0 = (wave & 1) * 64;
    const int wcol0 = (wave >> 1) * 64;
    const int aq = lane & 15;
    const int dq = lane >> 4;

    const int rA0 = t >> 2;                               // row 0..63 (issue 0)
    const int kcs = ((t & 3) - ((t >> 3) & 3)) & 3;       // swizzled k-chunk
    const int kc = kcs * 8;                               // element offset
    const int grA0 = min(row0 + rA0, M_TOT - 1);
    const int grA1 = min(row0 + rA0 + 64, M_TOT - 1);
    const int gcB0 = col0 + rA0;
    const int gcB1 = col0 + rA0 + 64;
    const size_t aoff0 = (size_t)grA0 * K_ + kc;
    const size_t aoff1 = (size_t)grA1 * K_ + kc;
    const size_t boff0 = (size_t)gcB0 * K_ + kc;
    const size_t boff1 = (size_t)gcB1 * K_ + kc;
    const int swz = ((dq + (aq >> 1)) & 3) * 16;          // read-side position
    const int ldsw = wave * 1024;

    f32x4 acc[4][4] = {};
    bf16x8 afr[2][4], bfr[2][4];   // register-double-buffered fragments

#define STAGE(BI, TK) do {                                                     \
    const int k0_ = (TK) * 32;                                                 \
    char* la_ = lds + (BI) * 16384 + ldsw;                                     \
    char* lb_ = la_ + 8192;                                                    \
    __builtin_amdgcn_global_load_lds(                                          \
        (const __attribute__((address_space(1))) void*)(A + aoff0 + k0_),      \
        (__attribute__((address_space(3))) void*)la_, 16, 0, 0);               \
    __builtin_amdgcn_global_load_lds(                                          \
        (const __attribute__((address_space(1))) void*)(A + aoff1 + k0_),      \
        (__attribute__((address_space(3))) void*)(la_ + 4096), 16, 0, 0);      \
    __builtin_amdgcn_global_load_lds(                                          \
        (const __attribute__((address_space(1))) void*)(Bm + boff0 + k0_),     \
        (__attribute__((address_space(3))) void*)lb_, 16, 0, 0);               \
    __builtin_amdgcn_global_load_lds(                                          \
        (const __attribute__((address_space(1))) void*)(Bm + boff1 + k0_),     \
        (__attribute__((address_space(3))) void*)(lb_ + 4096), 16, 0, 0);      \
} while (0)

// Issue LDS->reg fragment loads for buffer BI into reg-set RI (no wait).
#define DSREAD(BI, RI) do {                                                    \
    const char* la_ = lds + (BI) * 16384;                                      \
    const char* lb_ = la_ + 8192;                                              \
    _Pragma("unroll")                                                          \
    for (int rb = 0; rb < 4; ++rb)                                             \
        afr[RI][rb] = *(const bf16x8*)(la_ + (wrow0 + rb * 16 + aq) * 64 + swz);\
    _Pragma("unroll")                                                          \
    for (int cb = 0; cb < 4; ++cb)                                             \
        bfr[RI][cb] = *(const bf16x8*)(lb_ + (wcol0 + cb * 16 + aq) * 64 + swz);\
} while (0)

// 16 reg-only MFMAs on reg-set RI (compiler inserts the precise lgkmcnt).
#define MFMAS(RI) do {                                                         \
    _Pragma("unroll")                                                          \
    for (int rb = 0; rb < 4; ++rb)                                             \
        _Pragma("unroll")                                                      \
        for (int cb = 0; cb < 4; ++cb)                                         \
            acc[rb][cb] = __builtin_amdgcn_mfma_f32_16x16x32_bf16(             \
                afr[RI][rb], bfr[RI][cb], acc[rb][cb], 0, 0, 0);               \
} while (0)

// Slot-entry sync: tile t staged (counted vmcnt) AND this wave's ds_reads
// of the upcoming stage-target drained (lgkmcnt 0), then ONE barrier.
#define SYNC(NV) do {                                                          \
    asm volatile("s_waitcnt vmcnt(" #NV ") lgkmcnt(0)" ::: "memory");          \
    __builtin_amdgcn_sched_barrier(0);                                         \
    __builtin_amdgcn_s_barrier();                                              \
    __builtin_amdgcn_sched_barrier(0);                                         \
} while (0)

// Slot t: sync -> prefetch tile t+1 frags -> refill buf(t%3) with tile t+3
// -> compute tile t (reg-only MFMA).
#define SLOT(BN, RN, BS, RC, TKS) do {                                         \
    SYNC(4);                                                                   \
    DSREAD(BN, RN);                                                            \
    STAGE(BS, TKS);                                                            \
    MFMAS(RC);                                                                 \
} while (0)

    // Prologue: fill 3-deep LDS pipeline, load tile 0 fragments.
    STAGE(0, 0);
    STAGE(1, 1);
    STAGE(2, 2);
    asm volatile("s_waitcnt vmcnt(8)" ::: "memory");
    __builtin_amdgcn_sched_barrier(0);
    __builtin_amdgcn_s_barrier();
    __builtin_amdgcn_sched_barrier(0);
    DSREAD(0, 0);

    // Main: slots 0..59, period-6 unroll (buf = slot%3, reg = slot&1 static).
    for (int s6 = 0; s6 < 60; s6 += 6) {
        SLOT(1, 1, 0, 0, s6 + 3);
        SLOT(2, 0, 1, 1, s6 + 4);
        SLOT(0, 1, 2, 0, s6 + 5);
        SLOT(1, 0, 0, 1, s6 + 6);
        SLOT(2, 1, 1, 0, s6 + 7);
        SLOT(0, 0, 2, 1, s6 + 8);
    }
    // Epilogue: slots 60..63.
    SLOT(1, 1, 0, 0, 63);          // slot 60: stages tile 63 into buf0
    SYNC(4);                       // slot 61: tiles 62,63 in flight -> 62 done
    DSREAD(2, 0);
    MFMAS(1);
    SYNC(0);                       // slot 62: tile 63 landed
    DSREAD(0, 1);
    MFMAS(0);
    MFMAS(1);                      // slot 63

#undef STAGE
#undef DSREAD
#undef MFMAS
#undef SYNC
#undef SLOT

    #pragma unroll
    for (int rb = 0; rb < 4; ++rb) {
        int rowbase = row0 + wrow0 + rb * 16 + (lane >> 4) * 4;
        #pragma unroll
        for (int cb = 0; cb < 4; ++cb) {
            int col = col0 + wcol0 + cb * 16 + (lane & 15);
            #pragma unroll
            for (int i = 0; i < 4; ++i) {
                int row = rowbase + i;
                if (row < M_TOT)
                    Cm[(size_t)row * NO_ + col] = acc[rb][cb][i];
            }
        }
    }
}

// ---------------------------------------------------------------------------
extern "C" void kernel_launch(void* const* d_in, const int* in_sizes, int n_in,
                              void* d_out, int out_size, void* d_ws, size_t ws_size,
                              hipStream_t stream) {
    const float* x  = (const float*)d_in[0];
    const float* nb = (const float*)d_in[1];
    const float* W1 = (const float*)d_in[2];
    const float* W2 = (const float*)d_in[3];
    const float* Wc = (const float*)d_in[4];
    float* out = (float*)d_out;
    float* ws = (float*)d_ws;

    float* s1    = ws;            // 64 f
    float* s2    = ws + 64;       // 4096 f
    float* t     = ws + 4160;     // 131072 f
    float* rden  = ws + 135232;   // 4194304 f (B*F*F), stores 1/denom
    __hip_bfloat16* Abuf = (__hip_bfloat16*)(ws + 4329536);   // 4160*2048 bf16
    __hip_bfloat16* Bbuf = Abuf + (size_t)M_TOT * K_;         // 2048*2048 bf16

    hipLaunchKernelGGL(sums_wc_k, dim3(B_ * N_ + B_ + (K_ * NO_) / 1024),
                       dim3(256), 0, stream, x, nb, W1, W2, Wc, s1, s2, Bbuf);
    hipLaunchKernelGGL(t_k, dim3(B_ * C_), dim3(1024), 0, stream, nb, s1, s2, t);
    hipLaunchKernelGGL(denom_k, dim3(B_ * F_), dim3(256), 0, stream, x, t, rden);
    hipLaunchKernelGGL(znx_k, dim3(B_ * C_), dim3(256), 0, stream,
                       x, t, rden, nb, Abuf);
    hipLaunchKernelGGL(gemm_bf16_k, dim3(16, 33), dim3(256), 0, stream,
                       Abuf, Bbuf, out);
}

// Round 7
// 196.097 us; speedup vs baseline: 1.0491x; 1.0182x over previous
//
#include <hip/hip_runtime.h>
#include <hip/hip_bf16.h>
#include <math.h>

#define B_ 64
#define N_ 64
#define C_ 8
#define F_ 256
#define K_ 2048    // C_*F_
#define NO_ 2048   // OC_*OF_
#define M_TOT 4160 // 64 (zx rows) + 4096 (zn rows)

typedef __attribute__((ext_vector_type(8))) short bf16x8;  // 8 bf16 = 4 VGPRs
typedef __attribute__((ext_vector_type(4))) float f32x4;

__device__ __forceinline__ unsigned short bfbits(float f) {
    union { __hip_bfloat16 h; unsigned short u; } cv;
    cv.h = __float2bfloat16(f);
    return cv.u;
}

// ---------------------------------------------------------------------------
// Fused: s1[b], s2[b,n] reductions + Wc fp32->bf16 conversion.
// blk < 4096: s2;  4096..4159: s1;  >=4160: wc convert.
__global__ __launch_bounds__(256) void sums_wc_k(const float* __restrict__ x,
        const float* __restrict__ nb, const float* __restrict__ W1,
        const float* __restrict__ W2, const float* __restrict__ Wc,
        float* __restrict__ s1, float* __restrict__ s2,
        __hip_bfloat16* __restrict__ Bbuf) {
    int blk = blockIdx.x;
    int f = threadIdx.x;
    if (blk >= B_ * N_ + B_) {
        int i = (blk - (B_ * N_ + B_)) * 1024 + f * 4;
        float4 v = *(const float4*)(Wc + i);
        ushort4 u = { bfbits(v.x), bfbits(v.y), bfbits(v.z), bfbits(v.w) };
        *(ushort4*)(&Bbuf[i]) = u;            // one 8B store (was 4x 2B)
        return;
    }
    float val;
    if (blk < B_ * N_) {
        const float* base = nb + (size_t)blk * (C_ * F_);
        float wsum = 0.f;
        #pragma unroll
        for (int k = 0; k < C_; ++k) wsum += W2[k * F_ + f];
        float cs = 0.f;
        #pragma unroll
        for (int c = 0; c < C_; ++c) cs += base[c * F_ + f];
        val = cs * wsum;
    } else {
        int b = blk - B_ * N_;
        const float* base = x + (size_t)b * (C_ * F_);
        float wsum = 0.f;
        #pragma unroll
        for (int k = 0; k < C_; ++k) wsum += W1[k * F_ + f];
        float cs = 0.f;
        #pragma unroll
        for (int c = 0; c < C_; ++c) cs += base[c * F_ + f];
        val = cs * wsum;
    }
    #pragma unroll
    for (int off = 32; off > 0; off >>= 1) val += __shfl_down(val, off, 64);
    __shared__ float wred[4];
    int w = f >> 6;
    if ((f & 63) == 0) wred[w] = val;
    __syncthreads();
    if (f == 0) {
        float s = wred[0] + wred[1] + wred[2] + wred[3];
        if (blk < B_ * N_) s2[blk] = s;
        else s1[blk - B_ * N_] = s;
    }
}

// ---------------------------------------------------------------------------
// t[b,c,d] = s1[b] * sum_n nb[b,n,c,d] * s2[b,n]
__global__ __launch_bounds__(1024) void t_k(const float* __restrict__ nb,
        const float* __restrict__ s1, const float* __restrict__ s2,
        float* __restrict__ t) {
    int blk = blockIdx.x;  // b*C_ + c
    int b = blk / C_, c = blk % C_;
    int tid = threadIdx.x;
    int q = tid >> 8, d = tid & 255;
    const float* p = nb + ((size_t)(b * N_) * C_ + c) * F_ + d;
    const float* s2p = s2 + b * N_;
    float acc = 0.f;
    #pragma unroll
    for (int j = 0; j < 16; ++j) {
        int n = q * 16 + j;
        acc += p[(size_t)n * C_ * F_] * s2p[n];
    }
    __shared__ float part[4][F_];
    part[q][d] = acc;
    __syncthreads();
    if (tid < 256) {
        float s = part[0][d] + part[1][d] + part[2][d] + part[3][d];
        t[(size_t)blk * F_ + d] = s * s1[b];
    }
}

// ---------------------------------------------------------------------------
// rdenom[b,a,d] = 1 / (1e-7 + sum_c |sgnroot(x_a t_d + x_d t_a)|)
__global__ __launch_bounds__(256) void denom_k(const float* __restrict__ x,
        const float* __restrict__ t, float* __restrict__ rdenom) {
    int blk = blockIdx.x;  // b*F_ + a
    int b = blk >> 8, a = blk & 255;
    int d = threadIdx.x;
    float acc = 1e-7f;
    #pragma unroll
    for (int c = 0; c < C_; ++c) {
        size_t o = ((size_t)b * C_ + c) * F_;
        float xa = x[o + a], ta = t[o + a];
        float xd = x[o + d], td = t[o + d];
        float v = xa * td + xd * ta;
        float r = __builtin_amdgcn_sqrtf(fmaxf(fabsf(v), 1e-8f));
        acc += (v != 0.f) ? r : 0.f;
    }
    rdenom[(size_t)blk * F_ + d] = __builtin_amdgcn_rcpf(acc);
}

__device__ __forceinline__ float sgnroot_dev(float v) {
    float r = __builtin_amdgcn_sqrtf(fmaxf(fabsf(v), 1e-8f));
    return (v > 0.f) ? r : ((v < 0.f) ? -r : 0.f);
}

// ---------------------------------------------------------------------------
// Fused zx+zn via MFMA. One block per (b,c).
// R3 (verified, kept): packed 8B LDS staging writes; all-atile register
// accumulators; LDS-staged epilogue with coalesced 512B row copy-out.
#define ZNX_PAD 264  // row STRIDE in bf16: 256 data + 8 pad
__global__ __launch_bounds__(256, 2) void znx_k(const float* __restrict__ x,
        const float* __restrict__ t, const float* __restrict__ rdenom,
        const float* __restrict__ nb, __hip_bfloat16* __restrict__ Abuf) {
    int bc = blockIdx.x;
    int b = bc >> 3, c = bc & 7;
    int tid = threadIdx.x;
    int wave = tid >> 6, lane = tid & 63;
    __shared__ float xs[F_], ts[F_];
    __shared__ __hip_bfloat16 nbB[80 * ZNX_PAD];  // 42240 B

    xs[tid] = x[(size_t)bc * F_ + tid];
    ts[tid] = t[(size_t)bc * F_ + tid];
    {
        int r = tid >> 2, cs0 = (tid & 3) * 64;
        const float* src = nb + (((size_t)(b * N_ + r)) * C_ + c) * F_ + cs0;
        __hip_bfloat16* dst = nbB + r * ZNX_PAD + cs0;
        #pragma unroll
        for (int j = 0; j < 64; j += 4) {
            float4 v = *(const float4*)(src + j);
            ushort4 u = { bfbits(v.x), bfbits(v.y), bfbits(v.z), bfbits(v.w) };
            *(ushort4*)(&dst[j]) = u;          // 8B-aligned packed write
        }
    }
    if (tid < 64) {
        float4 v = *(const float4*)(x + (size_t)bc * F_ + tid * 4);
        ushort4 u = { bfbits(v.x), bfbits(v.y), bfbits(v.z), bfbits(v.w) };
        *(ushort4*)(&nbB[64 * ZNX_PAD + tid * 4]) = u;
    }
    {
        __hip_bfloat16 z = __float2bfloat16(0.f);
        #pragma unroll
        for (int j = 0; j < 16; ++j) {
            int o = 65 * ZNX_PAD + tid * 16 + j;
            if (o < 80 * ZNX_PAD) nbB[o] = z;
        }
    }
    __syncthreads();

    const int aq = lane & 15;
    const int dq = lane >> 4;
    f32x4 acc[4][5] = {};   // [atile][mt] -- all compile-time indexed
    #pragma unroll
    for (int atile = 0; atile < 4; ++atile) {
        int a = wave * 64 + atile * 16 + aq;
        float xa = xs[a], ta = ts[a];
        const float* drow = rdenom + ((size_t)b * F_ + a) * F_;
        #pragma unroll
        for (int kc = 0; kc < 8; ++kc) {
            int d0 = kc * 32 + dq * 8;
            float4 xv0 = *(const float4*)(xs + d0);
            float4 xv1 = *(const float4*)(xs + d0 + 4);
            float4 tv0 = *(const float4*)(ts + d0);
            float4 tv1 = *(const float4*)(ts + d0 + 4);
            float4 dn0 = *(const float4*)(drow + d0);
            float4 dn1 = *(const float4*)(drow + d0 + 4);
            float xv[8] = {xv0.x, xv0.y, xv0.z, xv0.w, xv1.x, xv1.y, xv1.z, xv1.w};
            float tv[8] = {tv0.x, tv0.y, tv0.z, tv0.w, tv1.x, tv1.y, tv1.z, tv1.w};
            float dn[8] = {dn0.x, dn0.y, dn0.z, dn0.w, dn1.x, dn1.y, dn1.z, dn1.w};
            union { bf16x8 v; __hip_bfloat16 h[8]; } bu;
            #pragma unroll
            for (int j = 0; j < 8; ++j) {
                float g = sgnroot_dev(xa * tv[j] + xv[j] * ta);
                bu.h[j] = __float2bfloat16(g * dn[j]);   // dn = 1/denom
            }
            #pragma unroll
            for (int mt = 0; mt < 5; ++mt) {
                bf16x8 af = *(const bf16x8*)(nbB + (mt * 16 + aq) * ZNX_PAD
                                             + kc * 32 + dq * 8);
                acc[atile][mt] = __builtin_amdgcn_mfma_f32_16x16x32_bf16(
                    af, bu.v, acc[atile][mt], 0, 0, 0);
            }
        }
    }

    // ---- epilogue: stage [65 rows x 256 cols] bf16 tile into nbB, then
    //      copy out as full coalesced rows (one 512B row per wave per iter).
    __syncthreads();   // all waves done READING nbB before overwrite
    #pragma unroll
    for (int atile = 0; atile < 4; ++atile) {
        int a = wave * 64 + atile * 16 + aq;
        #pragma unroll
        for (int mt = 0; mt < 4; ++mt) {
            #pragma unroll
            for (int i = 0; i < 4; ++i) {
                int n = mt * 16 + dq * 4 + i;
                nbB[n * ZNX_PAD + a] = __float2bfloat16(acc[atile][mt][i]);
            }
        }
        if (dq == 0)
            nbB[64 * ZNX_PAD + a] = __float2bfloat16(acc[atile][4][0]);
    }
    __syncthreads();
    // 65 rows x 512B = 4160 8B-chunks; chunk q -> row q>>6, bf16 off (q&63)*4
    for (int it = 0; it < 17; ++it) {
        int q = it * 256 + tid;
        if (q < 4160) {
            int row = q >> 6;
            int off = (q & 63) * 4;
            ushort4 u = *(const ushort4*)(&nbB[row * ZNX_PAD + off]);
            int grow = (row < 64) ? (64 + b * N_ + row) : b;
            *(ushort4*)(&Abuf[(size_t)grow * K_ + c * F_ + off]) = u;
        }
    }
}

// ---------------------------------------------------------------------------
// C[M_TOT, 2048] = A[M_TOT, 2048] @ B[2048, 2048]^T, bf16 in, fp32 out.
// R7: BK doubled 32->64 -- 32 slots instead of 64, halving per-slot fixed
// overhead (loop, rendezvous, issue sequences) relative to MFMA work
// (32 MFMA/wave/slot). 2 LDS buffers x 32 KiB (2 blocks/CU, grid-capped
// at 2.06 anyway so no occupancy loss -- m132's failure mode absent).
// Rows are now 128B -> NEW XOR swizzle (G4 / rule #21, both-sides):
//   write: linear gload_lds dest; per-lane global source pre-swizzled
//          kce = ((t&7) ^ ((t>>3)&7)) * 8
//   read:  slot = (kk*4+dq) ^ (aq&7)  -> 16-lane groups cover 8 slots x2
//          = 2-way aliasing = free (m136).
// T1 XCD swizzle kept (FETCH 77->67.7MB verified R6).
__global__ __launch_bounds__(256, 2) void gemm_bf16_k(
        const __hip_bfloat16* __restrict__ A,
        const __hip_bfloat16* __restrict__ Bm,
        float* __restrict__ Cm) {
    __shared__ char lds[65536] __attribute__((aligned(16)));  // 2 x (16K A + 16K B)
    const int t = threadIdx.x;
    const int wave = t >> 6;
    const int lane = t & 63;
    // T1: bijective XCD swizzle over 528 = 8 * 66 blocks.
    const int bidlin = blockIdx.y * 16 + blockIdx.x;
    const int bsw = (bidlin & 7) * 66 + (bidlin >> 3);
    const int col0 = (bsw & 15) * 128;
    const int row0 = (bsw >> 4) * 128;
    const int wrow0 = (wave & 1) * 64;
    const int wcol0 = (wave >> 1) * 64;
    const int aq = lane & 15;
    const int dq = lane >> 4;

    // Staging geometry: thread t covers row (t>>3)+i*32 (i=0..3 per matrix),
    // 16B chunk at lds-slot (t&7); global source slot is XOR'd by (row&7).
    const int srow = t >> 3;                      // 0..31
    const int kce = (((t & 7) ^ (srow & 7)) * 8); // pre-swizzled k-elem offset
    size_t aoffs[4], boffs[4];
    #pragma unroll
    for (int i = 0; i < 4; ++i) {
        aoffs[i] = (size_t)min(row0 + srow + i * 32, M_TOT - 1) * K_ + kce;
        boffs[i] = (size_t)(col0 + srow + i * 32) * K_ + kce;
    }
    const int ldst = t * 16;                      // linear dest chunk

    // Read-side: row&7 == aq&7 (wrow0, rb*16 are mults of 8).
    const int sx = aq & 7;                        // slot XOR key
    int arow[4], brow[4];
    #pragma unroll
    for (int rb = 0; rb < 4; ++rb) {
        arow[rb] = (wrow0 + rb * 16 + aq) * 128;
        brow[rb] = (wcol0 + rb * 16 + aq) * 128;
    }
    int soff[2];   // byte offset of (kk,dq) slot after XOR
    #pragma unroll
    for (int kk = 0; kk < 2; ++kk) soff[kk] = ((kk * 4 + dq) ^ sx) * 16;

    f32x4 acc[4][4] = {};
    bf16x8 af[4][2], bf[4][2];

#define STAGE(BI, TK) do {                                                     \
    const int k0_ = (TK) * 64;                                                 \
    char* la_ = lds + (BI) * 32768 + ldst;                                     \
    char* lb_ = la_ + 16384;                                                   \
    _Pragma("unroll")                                                          \
    for (int i_ = 0; i_ < 4; ++i_)                                             \
        __builtin_amdgcn_global_load_lds(                                      \
            (const __attribute__((address_space(1))) void*)(A + aoffs[i_] + k0_),\
            (__attribute__((address_space(3))) void*)(la_ + i_ * 4096), 16, 0, 0);\
    _Pragma("unroll")                                                          \
    for (int i_ = 0; i_ < 4; ++i_)                                             \
        __builtin_amdgcn_global_load_lds(                                      \
            (const __attribute__((address_space(1))) void*)(Bm + boffs[i_] + k0_),\
            (__attribute__((address_space(3))) void*)(lb_ + i_ * 4096), 16, 0, 0);\
} while (0)

#define DSREAD(BI) do {                                                        \
    const char* la_ = lds + (BI) * 32768;                                      \
    const char* lb_ = la_ + 16384;                                             \
    _Pragma("unroll")                                                          \
    for (int rb = 0; rb < 4; ++rb) {                                           \
        af[rb][0] = *(const bf16x8*)(la_ + arow[rb] + soff[0]);                \
        af[rb][1] = *(const bf16x8*)(la_ + arow[rb] + soff[1]);                \
    }                                                                          \
    _Pragma("unroll")                                                          \
    for (int cb = 0; cb < 4; ++cb) {                                           \
        bf[cb][0] = *(const bf16x8*)(lb_ + brow[cb] + soff[0]);                \
        bf[cb][1] = *(const bf16x8*)(lb_ + brow[cb] + soff[1]);                \
    }                                                                          \
} while (0)

#define MFMAS() do {                                                           \
    _Pragma("unroll")                                                          \
    for (int rb = 0; rb < 4; ++rb)                                             \
        _Pragma("unroll")                                                      \
        for (int cb = 0; cb < 4; ++cb) {                                       \
            acc[rb][cb] = __builtin_amdgcn_mfma_f32_16x16x32_bf16(             \
                af[rb][0], bf[cb][0], acc[rb][cb], 0, 0, 0);                   \
            acc[rb][cb] = __builtin_amdgcn_mfma_f32_16x16x32_bf16(             \
                af[rb][1], bf[cb][1], acc[rb][cb], 0, 0, 0);                   \
        }                                                                      \
} while (0)

#define SYNCV(N) do {                                                          \
    asm volatile("s_waitcnt vmcnt(" #N ")" ::: "memory");                      \
    __builtin_amdgcn_sched_barrier(0);                                         \
    __builtin_amdgcn_s_barrier();                                              \
    __builtin_amdgcn_sched_barrier(0);                                         \
} while (0)

// Slot t: entry sync (tile t landed; t+1's 8 loads in flight) -> ds_read
// tile t frags -> drain own reads + barrier (all waves' reads of buf done)
// -> overwrite buf with tile t+2 -> 32 MFMA (vmem issue hides under them).
#define SLOT(BI, TKS) do {                                                     \
    SYNCV(8);                                                                  \
    DSREAD(BI);                                                                \
    asm volatile("s_waitcnt lgkmcnt(0)" ::: "memory");                         \
    __builtin_amdgcn_sched_barrier(0);                                         \
    __builtin_amdgcn_s_barrier();                                              \
    __builtin_amdgcn_sched_barrier(0);                                         \
    STAGE(BI, TKS);                                                            \
    __builtin_amdgcn_sched_barrier(0);                                         \
    MFMAS();                                                                   \
} while (0)

    // Prologue: 2-deep fill (16 loads in flight per thread).
    STAGE(0, 0);
    STAGE(1, 1);

    // Slots 0..29 (15 x 2, static buffer index).
    for (int tt = 0; tt < 30; tt += 2) {
        SLOT(0, tt + 2);
        SLOT(1, tt + 3);
    }
    // Slot 30: tile 30 in buf0 (tile 31's 8 loads still in flight).
    SYNCV(8);
    DSREAD(0);
    MFMAS();
    // Slot 31: drain; tile 31 in buf1.
    SYNCV(0);
    DSREAD(1);
    MFMAS();

#undef STAGE
#undef DSREAD
#undef MFMAS
#undef SYNCV
#undef SLOT

    #pragma unroll
    for (int rb = 0; rb < 4; ++rb) {
        int rowbase = row0 + wrow0 + rb * 16 + (lane >> 4) * 4;
        #pragma unroll
        for (int cb = 0; cb < 4; ++cb) {
            int col = col0 + wcol0 + cb * 16 + (lane & 15);
            #pragma unroll
            for (int i = 0; i < 4; ++i) {
                int row = rowbase + i;
                if (row < M_TOT)
                    Cm[(size_t)row * NO_ + col] = acc[rb][cb][i];
            }
        }
    }
}

// ---------------------------------------------------------------------------
extern "C" void kernel_launch(void* const* d_in, const int* in_sizes, int n_in,
                              void* d_out, int out_size, void* d_ws, size_t ws_size,
                              hipStream_t stream) {
    const float* x  = (const float*)d_in[0];
    const float* nb = (const float*)d_in[1];
    const float* W1 = (const float*)d_in[2];
    const float* W2 = (const float*)d_in[3];
    const float* Wc = (const float*)d_in[4];
    float* out = (float*)d_out;
    float* ws = (float*)d_ws;

    float* s1    = ws;            // 64 f
    float* s2    = ws + 64;       // 4096 f
    float* t     = ws + 4160;     // 131072 f
    float* rden  = ws + 135232;   // 4194304 f (B*F*F), stores 1/denom
    __hip_bfloat16* Abuf = (__hip_bfloat16*)(ws + 4329536);   // 4160*2048 bf16
    __hip_bfloat16* Bbuf = Abuf + (size_t)M_TOT * K_;         // 2048*2048 bf16

    hipLaunchKernelGGL(sums_wc_k, dim3(B_ * N_ + B_ + (K_ * NO_) / 1024),
                       dim3(256), 0, stream, x, nb, W1, W2, Wc, s1, s2, Bbuf);
    hipLaunchKernelGGL(t_k, dim3(B_ * C_), dim3(1024), 0, stream, nb, s1, s2, t);
    hipLaunchKernelGGL(denom_k, dim3(B_ * F_), dim3(256), 0, stream, x, t, rden);
    hipLaunchKernelGGL(znx_k, dim3(B_ * C_), dim3(256), 0, stream,
                       x, t, rden, nb, Abuf);
    hipLaunchKernelGGL(gemm_bf16_k, dim3(16, 33), dim3(256), 0, stream,
                       Abuf, Bbuf, out);
}

// Round 8
// 193.942 us; speedup vs baseline: 1.0607x; 1.0111x over previous
//
#include <hip/hip_runtime.h>
#include <hip/hip_bf16.h>
#include <math.h>

#define B_ 64
#define N_ 64
#define C_ 8
#define F_ 256
#define K_ 2048    // C_*F_
#define NO_ 2048   // OC_*OF_
#define M_TOT 4160 // 64 (zx rows) + 4096 (zn rows)

typedef __attribute__((ext_vector_type(8))) short bf16x8;  // 8 bf16 = 4 VGPRs
typedef __attribute__((ext_vector_type(4))) float f32x4;

__device__ __forceinline__ unsigned short bfbits(float f) {
    union { __hip_bfloat16 h; unsigned short u; } cv;
    cv.h = __float2bfloat16(f);
    return cv.u;
}

// ---------------------------------------------------------------------------
// Fused: s1[b], s2[b,n] reductions + Wc fp32->bf16 conversion.
// blk < 4096: s2;  4096..4159: s1;  >=4160: wc convert.
__global__ __launch_bounds__(256) void sums_wc_k(const float* __restrict__ x,
        const float* __restrict__ nb, const float* __restrict__ W1,
        const float* __restrict__ W2, const float* __restrict__ Wc,
        float* __restrict__ s1, float* __restrict__ s2,
        __hip_bfloat16* __restrict__ Bbuf) {
    int blk = blockIdx.x;
    int f = threadIdx.x;
    if (blk >= B_ * N_ + B_) {
        int i = (blk - (B_ * N_ + B_)) * 1024 + f * 4;
        float4 v = *(const float4*)(Wc + i);
        ushort4 u = { bfbits(v.x), bfbits(v.y), bfbits(v.z), bfbits(v.w) };
        *(ushort4*)(&Bbuf[i]) = u;            // one 8B store (was 4x 2B)
        return;
    }
    float val;
    if (blk < B_ * N_) {
        const float* base = nb + (size_t)blk * (C_ * F_);
        float wsum = 0.f;
        #pragma unroll
        for (int k = 0; k < C_; ++k) wsum += W2[k * F_ + f];
        float cs = 0.f;
        #pragma unroll
        for (int c = 0; c < C_; ++c) cs += base[c * F_ + f];
        val = cs * wsum;
    } else {
        int b = blk - B_ * N_;
        const float* base = x + (size_t)b * (C_ * F_);
        float wsum = 0.f;
        #pragma unroll
        for (int k = 0; k < C_; ++k) wsum += W1[k * F_ + f];
        float cs = 0.f;
        #pragma unroll
        for (int c = 0; c < C_; ++c) cs += base[c * F_ + f];
        val = cs * wsum;
    }
    #pragma unroll
    for (int off = 32; off > 0; off >>= 1) val += __shfl_down(val, off, 64);
    __shared__ float wred[4];
    int w = f >> 6;
    if ((f & 63) == 0) wred[w] = val;
    __syncthreads();
    if (f == 0) {
        float s = wred[0] + wred[1] + wred[2] + wred[3];
        if (blk < B_ * N_) s2[blk] = s;
        else s1[blk - B_ * N_] = s;
    }
}

// ---------------------------------------------------------------------------
// t[b,c,d] = s1[b] * sum_n nb[b,n,c,d] * s2[b,n]
__global__ __launch_bounds__(1024) void t_k(const float* __restrict__ nb,
        const float* __restrict__ s1, const float* __restrict__ s2,
        float* __restrict__ t) {
    int blk = blockIdx.x;  // b*C_ + c
    int b = blk / C_, c = blk % C_;
    int tid = threadIdx.x;
    int q = tid >> 8, d = tid & 255;
    const float* p = nb + ((size_t)(b * N_) * C_ + c) * F_ + d;
    const float* s2p = s2 + b * N_;
    float acc = 0.f;
    #pragma unroll
    for (int j = 0; j < 16; ++j) {
        int n = q * 16 + j;
        acc += p[(size_t)n * C_ * F_] * s2p[n];
    }
    __shared__ float part[4][F_];
    part[q][d] = acc;
    __syncthreads();
    if (tid < 256) {
        float s = part[0][d] + part[1][d] + part[2][d] + part[3][d];
        t[(size_t)blk * F_ + d] = s * s1[b];
    }
}

// ---------------------------------------------------------------------------
// rdenom[b,a,d] = 1 / (1e-7 + sum_c |sgnroot(x_a t_d + x_d t_a)|)
// R8: block index transposed to blk = a*64 + b so all 256 a-blocks of a
// given b share blockIdx%8 -> same XCD -> the x[b]/t[b] slabs (16 KB) are
// fetched into ONE L2 and hit 255x (was: scattered across 8 XCDs, 268 MB
// of L3-level re-reads).
__global__ __launch_bounds__(256) void denom_k(const float* __restrict__ x,
        const float* __restrict__ t, float* __restrict__ rdenom) {
    int blk = blockIdx.x;
    int b = blk & 63, a = blk >> 6;   // idx = a*64+b -> %8 == b%8
    int d = threadIdx.x;
    float acc = 1e-7f;
    #pragma unroll
    for (int c = 0; c < C_; ++c) {
        size_t o = ((size_t)b * C_ + c) * F_;
        float xa = x[o + a], ta = t[o + a];
        float xd = x[o + d], td = t[o + d];
        float v = xa * td + xd * ta;
        float r = __builtin_amdgcn_sqrtf(fmaxf(fabsf(v), 1e-8f));
        acc += (v != 0.f) ? r : 0.f;
    }
    rdenom[((size_t)b * F_ + a) * F_ + d] = __builtin_amdgcn_rcpf(acc);
}

__device__ __forceinline__ float sgnroot_dev(float v) {
    float r = __builtin_amdgcn_sqrtf(fmaxf(fabsf(v), 1e-8f));
    return (v > 0.f) ? r : ((v < 0.f) ? -r : 0.f);
}

// ---------------------------------------------------------------------------
// Fused zx+zn via MFMA. One block per (b,c).
// R3 (verified, kept): packed 8B LDS staging writes; all-atile register
// accumulators; LDS-staged epilogue with coalesced 512B row copy-out.
// R8: block index transposed to bc = c*64 + b so the 8 c-blocks of a given
// b share blockIdx%8 -> same XCD -> the 256 KB rden[b] slab is fetched into
// ONE L2 and hit 7x (was: 8 XCDs each refetching it; 134 MB of re-reads).
#define ZNX_PAD 264  // row STRIDE in bf16: 256 data + 8 pad
__global__ __launch_bounds__(256, 2) void znx_k(const float* __restrict__ x,
        const float* __restrict__ t, const float* __restrict__ rdenom,
        const float* __restrict__ nb, __hip_bfloat16* __restrict__ Abuf) {
    int bcid = blockIdx.x;
    int b = bcid & 63, c = bcid >> 6;  // idx = c*64+b -> %8 == b%8
    int bc = b * 8 + c;                // storage-order index (unchanged)
    int tid = threadIdx.x;
    int wave = tid >> 6, lane = tid & 63;
    __shared__ float xs[F_], ts[F_];
    __shared__ __hip_bfloat16 nbB[80 * ZNX_PAD];  // 42240 B

    xs[tid] = x[(size_t)bc * F_ + tid];
    ts[tid] = t[(size_t)bc * F_ + tid];
    {
        int r = tid >> 2, cs0 = (tid & 3) * 64;
        const float* src = nb + (((size_t)(b * N_ + r)) * C_ + c) * F_ + cs0;
        __hip_bfloat16* dst = nbB + r * ZNX_PAD + cs0;
        #pragma unroll
        for (int j = 0; j < 64; j += 4) {
            float4 v = *(const float4*)(src + j);
            ushort4 u = { bfbits(v.x), bfbits(v.y), bfbits(v.z), bfbits(v.w) };
            *(ushort4*)(&dst[j]) = u;          // 8B-aligned packed write
        }
    }
    if (tid < 64) {
        float4 v = *(const float4*)(x + (size_t)bc * F_ + tid * 4);
        ushort4 u = { bfbits(v.x), bfbits(v.y), bfbits(v.z), bfbits(v.w) };
        *(ushort4*)(&nbB[64 * ZNX_PAD + tid * 4]) = u;
    }
    {
        __hip_bfloat16 z = __float2bfloat16(0.f);
        #pragma unroll
        for (int j = 0; j < 16; ++j) {
            int o = 65 * ZNX_PAD + tid * 16 + j;
            if (o < 80 * ZNX_PAD) nbB[o] = z;
        }
    }
    __syncthreads();

    const int aq = lane & 15;
    const int dq = lane >> 4;
    f32x4 acc[4][5] = {};   // [atile][mt] -- all compile-time indexed
    #pragma unroll
    for (int atile = 0; atile < 4; ++atile) {
        int a = wave * 64 + atile * 16 + aq;
        float xa = xs[a], ta = ts[a];
        const float* drow = rdenom + ((size_t)b * F_ + a) * F_;
        #pragma unroll
        for (int kc = 0; kc < 8; ++kc) {
            int d0 = kc * 32 + dq * 8;
            float4 xv0 = *(const float4*)(xs + d0);
            float4 xv1 = *(const float4*)(xs + d0 + 4);
            float4 tv0 = *(const float4*)(ts + d0);
            float4 tv1 = *(const float4*)(ts + d0 + 4);
            float4 dn0 = *(const float4*)(drow + d0);
            float4 dn1 = *(const float4*)(drow + d0 + 4);
            float xv[8] = {xv0.x, xv0.y, xv0.z, xv0.w, xv1.x, xv1.y, xv1.z, xv1.w};
            float tv[8] = {tv0.x, tv0.y, tv0.z, tv0.w, tv1.x, tv1.y, tv1.z, tv1.w};
            float dn[8] = {dn0.x, dn0.y, dn0.z, dn0.w, dn1.x, dn1.y, dn1.z, dn1.w};
            union { bf16x8 v; __hip_bfloat16 h[8]; } bu;
            #pragma unroll
            for (int j = 0; j < 8; ++j) {
                float g = sgnroot_dev(xa * tv[j] + xv[j] * ta);
                bu.h[j] = __float2bfloat16(g * dn[j]);   // dn = 1/denom
            }
            #pragma unroll
            for (int mt = 0; mt < 5; ++mt) {
                bf16x8 af = *(const bf16x8*)(nbB + (mt * 16 + aq) * ZNX_PAD
                                             + kc * 32 + dq * 8);
                acc[atile][mt] = __builtin_amdgcn_mfma_f32_16x16x32_bf16(
                    af, bu.v, acc[atile][mt], 0, 0, 0);
            }
        }
    }

    // ---- epilogue: stage [65 rows x 256 cols] bf16 tile into nbB, then
    //      copy out as full coalesced rows (one 512B row per wave per iter).
    __syncthreads();   // all waves done READING nbB before overwrite
    #pragma unroll
    for (int atile = 0; atile < 4; ++atile) {
        int a = wave * 64 + atile * 16 + aq;
        #pragma unroll
        for (int mt = 0; mt < 4; ++mt) {
            #pragma unroll
            for (int i = 0; i < 4; ++i) {
                int n = mt * 16 + dq * 4 + i;
                nbB[n * ZNX_PAD + a] = __float2bfloat16(acc[atile][mt][i]);
            }
        }
        if (dq == 0)
            nbB[64 * ZNX_PAD + a] = __float2bfloat16(acc[atile][4][0]);
    }
    __syncthreads();
    // 65 rows x 512B = 4160 8B-chunks; chunk q -> row q>>6, bf16 off (q&63)*4
    for (int it = 0; it < 17; ++it) {
        int q = it * 256 + tid;
        if (q < 4160) {
            int row = q >> 6;
            int off = (q & 63) * 4;
            ushort4 u = *(const ushort4*)(&nbB[row * ZNX_PAD + off]);
            int grow = (row < 64) ? (64 + b * N_ + row) : b;
            *(ushort4*)(&Abuf[(size_t)grow * K_ + c * F_ + off]) = u;
        }
    }
}

// ---------------------------------------------------------------------------
// C[M_TOT, 2048] = A[M_TOT, 2048] @ B[2048, 2048]^T, bf16 in, fp32 out.
// R7 (verified: 63.2 -> 51.0 us, MfmaUtil 27.6%): BK=64, 32 slots, 2 LDS
// buffers x 32 KiB, counted-vmcnt; XOR swizzle both-sides; T1 XCD swizzle.
// Unchanged in R8.
__global__ __launch_bounds__(256, 2) void gemm_bf16_k(
        const __hip_bfloat16* __restrict__ A,
        const __hip_bfloat16* __restrict__ Bm,
        float* __restrict__ Cm) {
    __shared__ char lds[65536] __attribute__((aligned(16)));  // 2 x (16K A + 16K B)
    const int t = threadIdx.x;
    const int wave = t >> 6;
    const int lane = t & 63;
    // T1: bijective XCD swizzle over 528 = 8 * 66 blocks.
    const int bidlin = blockIdx.y * 16 + blockIdx.x;
    const int bsw = (bidlin & 7) * 66 + (bidlin >> 3);
    const int col0 = (bsw & 15) * 128;
    const int row0 = (bsw >> 4) * 128;
    const int wrow0 = (wave & 1) * 64;
    const int wcol0 = (wave >> 1) * 64;
    const int aq = lane & 15;
    const int dq = lane >> 4;

    // Staging geometry: thread t covers row (t>>3)+i*32 (i=0..3 per matrix),
    // 16B chunk at lds-slot (t&7); global source slot is XOR'd by (row&7).
    const int srow = t >> 3;                      // 0..31
    const int kce = (((t & 7) ^ (srow & 7)) * 8); // pre-swizzled k-elem offset
    size_t aoffs[4], boffs[4];
    #pragma unroll
    for (int i = 0; i < 4; ++i) {
        aoffs[i] = (size_t)min(row0 + srow + i * 32, M_TOT - 1) * K_ + kce;
        boffs[i] = (size_t)(col0 + srow + i * 32) * K_ + kce;
    }
    const int ldst = t * 16;                      // linear dest chunk

    // Read-side: row&7 == aq&7 (wrow0, rb*16 are mults of 8).
    const int sx = aq & 7;                        // slot XOR key
    int arow[4], brow[4];
    #pragma unroll
    for (int rb = 0; rb < 4; ++rb) {
        arow[rb] = (wrow0 + rb * 16 + aq) * 128;
        brow[rb] = (wcol0 + rb * 16 + aq) * 128;
    }
    int soff[2];   // byte offset of (kk,dq) slot after XOR
    #pragma unroll
    for (int kk = 0; kk < 2; ++kk) soff[kk] = ((kk * 4 + dq) ^ sx) * 16;

    f32x4 acc[4][4] = {};
    bf16x8 af[4][2], bf[4][2];

#define STAGE(BI, TK) do {                                                     \
    const int k0_ = (TK) * 64;                                                 \
    char* la_ = lds + (BI) * 32768 + ldst;                                     \
    char* lb_ = la_ + 16384;                                                   \
    _Pragma("unroll")                                                          \
    for (int i_ = 0; i_ < 4; ++i_)                                             \
        __builtin_amdgcn_global_load_lds(                                      \
            (const __attribute__((address_space(1))) void*)(A + aoffs[i_] + k0_),\
            (__attribute__((address_space(3))) void*)(la_ + i_ * 4096), 16, 0, 0);\
    _Pragma("unroll")                                                          \
    for (int i_ = 0; i_ < 4; ++i_)                                             \
        __builtin_amdgcn_global_load_lds(                                      \
            (const __attribute__((address_space(1))) void*)(Bm + boffs[i_] + k0_),\
            (__attribute__((address_space(3))) void*)(lb_ + i_ * 4096), 16, 0, 0);\
} while (0)

#define DSREAD(BI) do {                                                        \
    const char* la_ = lds + (BI) * 32768;                                      \
    const char* lb_ = la_ + 16384;                                             \
    _Pragma("unroll")                                                          \
    for (int rb = 0; rb < 4; ++rb) {                                           \
        af[rb][0] = *(const bf16x8*)(la_ + arow[rb] + soff[0]);                \
        af[rb][1] = *(const bf16x8*)(la_ + arow[rb] + soff[1]);                \
    }                                                                          \
    _Pragma("unroll")                                                          \
    for (int cb = 0; cb < 4; ++cb) {                                           \
        bf[cb][0] = *(const bf16x8*)(lb_ + brow[cb] + soff[0]);                \
        bf[cb][1] = *(const bf16x8*)(lb_ + brow[cb] + soff[1]);                \
    }                                                                          \
} while (0)

#define MFMAS() do {                                                           \
    _Pragma("unroll")                                                          \
    for (int rb = 0; rb < 4; ++rb)                                             \
        _Pragma("unroll")                                                      \
        for (int cb = 0; cb < 4; ++cb) {                                       \
            acc[rb][cb] = __builtin_amdgcn_mfma_f32_16x16x32_bf16(             \
                af[rb][0], bf[cb][0], acc[rb][cb], 0, 0, 0);                   \
            acc[rb][cb] = __builtin_amdgcn_mfma_f32_16x16x32_bf16(             \
                af[rb][1], bf[cb][1], acc[rb][cb], 0, 0, 0);                   \
        }                                                                      \
} while (0)

#define SYNCV(N) do {                                                          \
    asm volatile("s_waitcnt vmcnt(" #N ")" ::: "memory");                      \
    __builtin_amdgcn_sched_barrier(0);                                         \
    __builtin_amdgcn_s_barrier();                                              \
    __builtin_amdgcn_sched_barrier(0);                                         \
} while (0)

// Slot t: entry sync (tile t landed; t+1's 8 loads in flight) -> ds_read
// tile t frags -> drain own reads + barrier (all waves' reads of buf done)
// -> overwrite buf with tile t+2 -> 32 MFMA (vmem issue hides under them).
#define SLOT(BI, TKS) do {                                                     \
    SYNCV(8);                                                                  \
    DSREAD(BI);                                                                \
    asm volatile("s_waitcnt lgkmcnt(0)" ::: "memory");                         \
    __builtin_amdgcn_sched_barrier(0);                                         \
    __builtin_amdgcn_s_barrier();                                              \
    __builtin_amdgcn_sched_barrier(0);                                         \
    STAGE(BI, TKS);                                                            \
    __builtin_amdgcn_sched_barrier(0);                                         \
    MFMAS();                                                                   \
} while (0)

    // Prologue: 2-deep fill (16 loads in flight per thread).
    STAGE(0, 0);
    STAGE(1, 1);

    // Slots 0..29 (15 x 2, static buffer index).
    for (int tt = 0; tt < 30; tt += 2) {
        SLOT(0, tt + 2);
        SLOT(1, tt + 3);
    }
    // Slot 30: tile 30 in buf0 (tile 31's 8 loads still in flight).
    SYNCV(8);
    DSREAD(0);
    MFMAS();
    // Slot 31: drain; tile 31 in buf1.
    SYNCV(0);
    DSREAD(1);
    MFMAS();

#undef STAGE
#undef DSREAD
#undef MFMAS
#undef SYNCV
#undef SLOT

    #pragma unroll
    for (int rb = 0; rb < 4; ++rb) {
        int rowbase = row0 + wrow0 + rb * 16 + (lane >> 4) * 4;
        #pragma unroll
        for (int cb = 0; cb < 4; ++cb) {
            int col = col0 + wcol0 + cb * 16 + (lane & 15);
            #pragma unroll
            for (int i = 0; i < 4; ++i) {
                int row = rowbase + i;
                if (row < M_TOT)
                    Cm[(size_t)row * NO_ + col] = acc[rb][cb][i];
            }
        }
    }
}

// ---------------------------------------------------------------------------
extern "C" void kernel_launch(void* const* d_in, const int* in_sizes, int n_in,
                              void* d_out, int out_size, void* d_ws, size_t ws_size,
                              hipStream_t stream) {
    const float* x  = (const float*)d_in[0];
    const float* nb = (const float*)d_in[1];
    const float* W1 = (const float*)d_in[2];
    const float* W2 = (const float*)d_in[3];
    const float* Wc = (const float*)d_in[4];
    float* out = (float*)d_out;
    float* ws = (float*)d_ws;

    float* s1    = ws;            // 64 f
    float* s2    = ws + 64;       // 4096 f
    float* t     = ws + 4160;     // 131072 f
    float* rden  = ws + 135232;   // 4194304 f (B*F*F), stores 1/denom
    __hip_bfloat16* Abuf = (__hip_bfloat16*)(ws + 4329536);   // 4160*2048 bf16
    __hip_bfloat16* Bbuf = Abuf + (size_t)M_TOT * K_;         // 2048*2048 bf16

    hipLaunchKernelGGL(sums_wc_k, dim3(B_ * N_ + B_ + (K_ * NO_) / 1024),
                       dim3(256), 0, stream, x, nb, W1, W2, Wc, s1, s2, Bbuf);
    hipLaunchKernelGGL(t_k, dim3(B_ * C_), dim3(1024), 0, stream, nb, s1, s2, t);
    hipLaunchKernelGGL(denom_k, dim3(B_ * F_), dim3(256), 0, stream, x, t, rden);
    hipLaunchKernelGGL(znx_k, dim3(B_ * C_), dim3(256), 0, stream,
                       x, t, rden, nb, Abuf);
    hipLaunchKernelGGL(gemm_bf16_k, dim3(16, 33), dim3(256), 0, stream,
                       Abuf, Bbuf, out);
}